// Round 7
// baseline (760.915 us; speedup 1.0000x reference)
//
#include <hip/hip_runtime.h>

typedef unsigned short ushort_t;
typedef unsigned int   u32;
typedef __attribute__((ext_vector_type(8))) short bf16x8;
typedef __attribute__((ext_vector_type(4))) float f32x4;

#define NNODES 100000
#define DIM    256
#define NEDGE  300000
#define KSTEPS 16           // BK = 32 over virtual K = [agg | xin] = 512
#define BROWS  64           // rows per block (4 row-tiles x 16)
#define SLICE  16384        // ushorts per 32-k B slice: 2 planes x 256 n x 32 k
// B slice layout (ushort units): plane*8192 + ct*512 + q*128 + nn*8 + j
// A tensors (x2 / h / agg2) are split-bf16 planes: row = [256 hi ushorts | 256 lo ushorts]
#define MFMA16 __builtin_amdgcn_mfma_f32_16x16x32_bf16

// ================= CSR build (counting sort by dst) =================

__global__ void count_kernel(const int* __restrict__ dst, int* __restrict__ cnt, int E) {
    int e = blockIdx.x * blockDim.x + threadIdx.x;
    if (e < E) atomicAdd(&cnt[dst[e]], 1);
}

__global__ void scan1(const int* __restrict__ cnt, int* __restrict__ partial, int n) {
    __shared__ int s[256];
    int i = blockIdx.x * 256 + threadIdx.x;
    s[threadIdx.x] = (i < n) ? cnt[i] : 0;
    __syncthreads();
    for (int off = 128; off > 0; off >>= 1) {
        if (threadIdx.x < off) s[threadIdx.x] += s[threadIdx.x + off];
        __syncthreads();
    }
    if (threadIdx.x == 0) partial[blockIdx.x] = s[0];
}

__global__ void scan2(int* __restrict__ partial, int nb) {
    __shared__ int s[512];
    int t = threadIdx.x;
    int orig = (t < nb) ? partial[t] : 0;
    s[t] = orig;
    __syncthreads();
    for (int off = 1; off < 512; off <<= 1) {
        int v = (t >= off) ? s[t - off] : 0;
        __syncthreads();
        s[t] += v;
        __syncthreads();
    }
    if (t < nb) partial[t] = s[t] - orig;  // exclusive
}

__global__ void scan3(const int* __restrict__ cnt, const int* __restrict__ partial,
                      int* __restrict__ row_start, int n) {
    __shared__ int s[256];
    int i = blockIdx.x * 256 + threadIdx.x;
    int v = (i < n) ? cnt[i] : 0;
    s[threadIdx.x] = v;
    __syncthreads();
    for (int off = 1; off < 256; off <<= 1) {
        int t = (threadIdx.x >= off) ? s[threadIdx.x - off] : 0;
        __syncthreads();
        s[threadIdx.x] += t;
        __syncthreads();
    }
    if (i < n) row_start[i] = partial[blockIdx.x] + s[threadIdx.x] - v;
}

__global__ void fill_csr(const int* __restrict__ src, const int* __restrict__ dst,
                         const int* __restrict__ row_start, int* __restrict__ cursor,
                         int* __restrict__ esrc, int E) {
    int e = blockIdx.x * blockDim.x + threadIdx.x;
    if (e < E) {
        int d = dst[e];
        int pos = row_start[d] + atomicAdd(&cursor[d], 1);
        esrc[pos] = src[e];
    }
}

// ================= split helpers =================

__device__ __forceinline__ float bfhi(unsigned u) { return __uint_as_float(u << 16); }
__device__ __forceinline__ float bflo(unsigned u) { return __uint_as_float(u & 0xFFFF0000u); }

// split 4 floats -> packed hi uint2 + lo uint2 (truncating split)
__device__ __forceinline__ void split4pack(float v0, float v1, float v2, float v3,
                                           uint2& hi, uint2& lo) {
    unsigned u0 = __float_as_uint(v0), u1 = __float_as_uint(v1);
    unsigned u2 = __float_as_uint(v2), u3 = __float_as_uint(v3);
    hi.x = (u0 >> 16) | (u1 & 0xFFFF0000u);
    hi.y = (u2 >> 16) | (u3 & 0xFFFF0000u);
    unsigned w0 = __float_as_uint(v0 - bflo(u0)), w1 = __float_as_uint(v1 - bflo(u1));
    unsigned w2 = __float_as_uint(v2 - bflo(u2)), w3 = __float_as_uint(v3 - bflo(u3));
    lo.x = (w0 >> 16) | (w1 & 0xFFFF0000u);
    lo.y = (w2 >> 16) | (w3 & 0xFFFF0000u);
}

// ================= x -> split-plane form (one-time) =================
__global__ __launch_bounds__(256) void split_x(const float* __restrict__ x,
                                               ushort_t* __restrict__ x2) {
    int idx = blockIdx.x * 256 + threadIdx.x;      // node*64 + lane
    if (idx >= NNODES * 64) return;
    int node = idx >> 6, lane = idx & 63;
    float4 v = ((const float4*)(x + (size_t)node * DIM))[lane];
    uint2 hi, lo;
    split4pack(v.x, v.y, v.z, v.w, hi, lo);
    *(uint2*)(x2 + (size_t)node * 512 + lane * 4)       = hi;
    *(uint2*)(x2 + (size_t)node * 512 + 256 + lane * 4) = lo;
}

// ================= aggregation: one wave per node, split-plane in/out =================
__global__ __launch_bounds__(256) void aggregate2(
    const int* __restrict__ esrc, const int* __restrict__ row_start,
    const int* __restrict__ cnt, const ushort_t* __restrict__ x2,
    ushort_t* __restrict__ agg2)
{
    int node = (blockIdx.x * blockDim.x + threadIdx.x) >> 6;
    int lane = threadIdx.x & 63;
    if (node >= NNODES) return;
    int start = row_start[node];
    int c = cnt[node];
    float a0 = 0.f, a1 = 0.f, a2 = 0.f, a3 = 0.f;
    for (int i = 0; i < c; i++) {
        int s = esrc[start + i];
        const uint2 h = *(const uint2*)(x2 + (size_t)s * 512 + lane * 4);
        const uint2 l = *(const uint2*)(x2 + (size_t)s * 512 + 256 + lane * 4);
        a0 += bfhi(h.x) + bfhi(l.x);
        a1 += bflo(h.x) + bflo(l.x);
        a2 += bfhi(h.y) + bfhi(l.y);
        a3 += bflo(h.y) + bflo(l.y);
    }
    float inv = (c > 0) ? 1.0f / (float)c : 0.0f;
    uint2 hi, lo;
    split4pack(a0 * inv, a1 * inv, a2 * inv, a3 * inv, hi, lo);
    *(uint2*)(agg2 + (size_t)node * 512 + lane * 4)       = hi;
    *(uint2*)(agg2 + (size_t)node * 512 + 256 + lane * 4) = lo;
}

// ========== weight split + swizzle into MFMA-fragment order (per-wave 1KB-contig frags) ==========
__global__ void conv_weights(const float* __restrict__ Wl, const float* __restrict__ Wr,
                             ushort_t* __restrict__ Bsw) {
    int idx = blockIdx.x * 256 + threadIdx.x;      // n*512 + k
    if (idx >= 256 * 512) return;
    int n = idx >> 9, k = idx & 511;
    float v = (k < DIM) ? Wl[n * DIM + k] : Wr[n * DIM + (k - DIM)];
    unsigned u = __float_as_uint(v);
    float lo = v - bflo(u);
    int ks = k >> 5, q = (k >> 3) & 3, j = k & 7;
    int ct = n >> 4, nn = n & 15;
    int base = ks * SLICE + ct * 512 + q * 128 + nn * 8 + j;
    Bsw[base]        = (ushort_t)(u >> 16);                      // hi plane
    Bsw[base + 8192] = (ushort_t)(__float_as_uint(lo) >> 16);    // lo plane
}

// ================= MFMA GEMM: out = [agg|xin] @ B^T + bias — NO LDS, no per-k-step barrier =====
// Theory: three schedules with a per-k-step __syncthreads all plateaued at ~128 us because the
// barrier couples all waves to the slowest load every iteration (~8K exposed cycles/iter).
// Here every wave free-runs: B fragments are read directly from the shared 512 KB Bsw
// (64-lane x 16B contiguous per instr; L2/L3-resident, same lines reused by all blocks),
// A fragments directly from the pre-split planes. 16 waves/CU self-stagger to hide latency.
// Wave = 4 row-tiles x 4 col-tiles (M=64, N=64): acc 64 VGPR + frags ~48 -> ~116 regs, no LDS.
// Block = 256 threads = 4 waves = 4 col-groups covering N=256; block owns 64 rows.
// RACE FIX (round 6): output is written in-place over xin2 (the block's own A rows), so a
// single __syncthreads() must separate the K-loop (all A-reads, consumed in-regs) from the
// epilogue — otherwise a fast wave overwrites rows a slow wave of the same block still reads.
__global__ __launch_bounds__(256, 4) void sage_gemm_mfma(
    const ushort_t* __restrict__ agg2, const ushort_t* __restrict__ xin2,
    const ushort_t* __restrict__ Bsw, const float* __restrict__ bias,
    void* __restrict__ outp, int M, int out_split)
{
    const int tid  = threadIdx.x;
    const int lane = tid & 63;
    const int cg   = tid >> 6;          // col-group 0..3
    const int lrow = lane & 15;
    const int quad = lane >> 4;

    const int rowbase = blockIdx.x * BROWS;
    int r[4];
    #pragma unroll
    for (int rt = 0; rt < 4; rt++)
        r[rt] = min(rowbase + rt * 16 + lrow, M - 1);   // clamped (tail block; stays in-block)
    const int kq = quad * 8;
    const int ctbase = cg * 4;          // 4 col-tiles of 16 -> N=64 per wave

    f32x4 acc[4][4];
    #pragma unroll
    for (int i = 0; i < 4; i++)
        #pragma unroll
        for (int j = 0; j < 4; j++)
            acc[i][j] = (f32x4){0.f, 0.f, 0.f, 0.f};

    #pragma unroll
    for (int ks = 0; ks < KSTEPS; ks++) {
        const ushort_t* ab = (ks < 8) ? agg2 : xin2;
        const int kk = (ks & 7) * 32 + kq;

        bf16x8 fh[4], fl[4];
        #pragma unroll
        for (int rt = 0; rt < 4; rt++) {
            const ushort_t* p = ab + (size_t)r[rt] * 512 + kk;
            fh[rt] = *(const bf16x8*)(p);
            fl[rt] = *(const bf16x8*)(p + 256);
        }

        const ushort_t* bp = Bsw + (size_t)ks * SLICE + ctbase * 512 + lane * 8;

        __builtin_amdgcn_s_setprio(1);
        #pragma unroll
        for (int ct = 0; ct < 4; ct++) {
            const bf16x8 bh = *(const bf16x8*)(bp + ct * 512);
            const bf16x8 bl = *(const bf16x8*)(bp + 8192 + ct * 512);
            #pragma unroll
            for (int rt = 0; rt < 4; rt++) {
                acc[rt][ct] = MFMA16(fh[rt], bh, acc[rt][ct], 0, 0, 0);
                acc[rt][ct] = MFMA16(fl[rt], bh, acc[rt][ct], 0, 0, 0);
                acc[rt][ct] = MFMA16(fh[rt], bl, acc[rt][ct], 0, 0, 0);
            }
        }
        __builtin_amdgcn_s_setprio(0);
    }

    // All A-reads are complete (consumed by MFMAs) once every thread reaches here;
    // the barrier makes that block-wide before any in-place epilogue write.
    __syncthreads();

    // ---- epilogue: bias (+relu+split for layers 1-2, f32 for layer 3) ----
    // C layout: col=lane&15, row=quad*4+reg
    #pragma unroll
    for (int ct = 0; ct < 4; ct++) {
        const int col = (ctbase + ct) * 16 + lrow;
        const float bv = bias[col];
        #pragma unroll
        for (int rt = 0; rt < 4; rt++) {
            const int row = rowbase + rt * 16 + quad * 4;
            #pragma unroll
            for (int rr = 0; rr < 4; rr++) {
                if (row + rr < M) {
                    float v = acc[rt][ct][rr] + bv;
                    if (out_split) {
                        v = fmaxf(v, 0.f);
                        unsigned u = __float_as_uint(v);
                        float lo = v - bflo(u);
                        ushort_t* o = (ushort_t*)outp + (size_t)(row + rr) * 512 + col;
                        o[0]   = (ushort_t)(u >> 16);
                        o[256] = (ushort_t)(__float_as_uint(lo) >> 16);
                    } else {
                        ((float*)outp)[(size_t)(row + rr) * DIM + col] = v;
                    }
                }
            }
        }
    }
}

extern "C" void kernel_launch(void* const* d_in, const int* in_sizes, int n_in,
                              void* d_out, int out_size, void* d_ws, size_t ws_size,
                              hipStream_t stream) {
    const int*   edge = (const int*)d_in[0];
    const int*   src  = edge;
    const int*   dst  = edge + NEDGE;
    const float* x    = (const float*)d_in[1];
    const float* Wl1  = (const float*)d_in[2];
    const float* Wr1  = (const float*)d_in[3];
    const float* b1   = (const float*)d_in[4];
    const float* Wl2  = (const float*)d_in[5];
    const float* Wr2  = (const float*)d_in[6];
    const float* b2   = (const float*)d_in[7];
    const float* Wl3  = (const float*)d_in[8];
    const float* Wr3  = (const float*)d_in[9];
    const float* b3   = (const float*)d_in[10];

    // workspace: agg2 (split-plane, N*512 ushorts = 102.4 MB) + CSR + Bsw  (~109 MB total)
    ushort_t* agg2      = (ushort_t*)d_ws;
    int*      cnt       = (int*)(agg2 + (size_t)NNODES * 512);
    int*      row_start = cnt + NNODES;
    int*      cursor    = row_start + NNODES;
    int*      partial   = cursor + NNODES;            // 512
    int*      esrc      = partial + 512;              // NEDGE
    ushort_t* Bsw       = (ushort_t*)(esrc + NEDGE);  // KSTEPS*SLICE ushorts (512 KB)

    // x2 / h1 / h2 all live in the d_out region (N*512 ushorts == N*256 f32 == out_size);
    // each GEMM rewrites it in-place (block-own rows), layer 3 leaves f32 output there.
    ushort_t* x2 = (ushort_t*)d_out;

    const int nScanBlocks = (NNODES + 255) / 256;

    // ---- CSR build (edge structure shared by all 3 layers) ----
    hipMemsetAsync(cnt, 0, NNODES * sizeof(int), stream);
    hipMemsetAsync(cursor, 0, NNODES * sizeof(int), stream);
    count_kernel<<<(NEDGE + 255) / 256, 256, 0, stream>>>(dst, cnt, NEDGE);
    scan1<<<nScanBlocks, 256, 0, stream>>>(cnt, partial, NNODES);
    scan2<<<1, 512, 0, stream>>>(partial, nScanBlocks);
    scan3<<<nScanBlocks, 256, 0, stream>>>(cnt, partial, row_start, NNODES);
    fill_csr<<<(NEDGE + 255) / 256, 256, 0, stream>>>(src, dst, row_start, cursor, esrc, NEDGE);

    split_x<<<(NNODES * 64 + 255) / 256, 256, 0, stream>>>(x, x2);

    const int aggBlocks  = (NNODES * 64 + 255) / 256;
    const int gemmBlocks = (NNODES + BROWS - 1) / BROWS;
    const int convBlocks = (256 * 512 + 255) / 256;

    // ---- layer 1 ----
    conv_weights<<<convBlocks, 256, 0, stream>>>(Wl1, Wr1, Bsw);
    aggregate2<<<aggBlocks, 256, 0, stream>>>(esrc, row_start, cnt, x2, agg2);
    sage_gemm_mfma<<<gemmBlocks, 256, 0, stream>>>(agg2, x2, Bsw, b1, (void*)x2, NNODES, 1);

    // ---- layer 2 ----
    conv_weights<<<convBlocks, 256, 0, stream>>>(Wl2, Wr2, Bsw);
    aggregate2<<<aggBlocks, 256, 0, stream>>>(esrc, row_start, cnt, x2, agg2);
    sage_gemm_mfma<<<gemmBlocks, 256, 0, stream>>>(agg2, x2, Bsw, b2, (void*)x2, NNODES, 1);

    // ---- layer 3 ----
    conv_weights<<<convBlocks, 256, 0, stream>>>(Wl3, Wr3, Bsw);
    aggregate2<<<aggBlocks, 256, 0, stream>>>(esrc, row_start, cnt, x2, agg2);
    sage_gemm_mfma<<<gemmBlocks, 256, 0, stream>>>(agg2, x2, Bsw, b3, d_out, NNODES, 0);
}

// Round 8
// 628.067 us; speedup vs baseline: 1.2115x; 1.2115x over previous
//
#include <hip/hip_runtime.h>

typedef unsigned short ushort_t;
typedef unsigned int   u32;
typedef __attribute__((ext_vector_type(8))) short bf16x8;
typedef __attribute__((ext_vector_type(4))) float f32x4;

#define NNODES 100000
#define DIM    256
#define NEDGE  300000
#define KSTEPS 16           // BK = 32 over virtual K = [agg | xin] = 512
#define BROWS  128          // rows per block (4 row-groups x 32 rows)
#define WCT    8            // col-tiles per wave (N split across 2 col-groups)
#define SLICE  16384        // ushorts per 32-k B slice: 2 planes x 256 n x 32 k
// B slice layout (ushort units): plane*8192 + ct*512 + q*128 + nn*8 + j
// A tensors (x2 / h / agg2) are split-bf16 planes: row = [256 hi ushorts | 256 lo ushorts]
#define MFMA16 __builtin_amdgcn_mfma_f32_16x16x32_bf16

// ================= CSR build (counting sort by dst) =================

__global__ void count_kernel(const int* __restrict__ dst, int* __restrict__ cnt, int E) {
    int e = blockIdx.x * blockDim.x + threadIdx.x;
    if (e < E) atomicAdd(&cnt[dst[e]], 1);
}

__global__ void scan1(const int* __restrict__ cnt, int* __restrict__ partial, int n) {
    __shared__ int s[256];
    int i = blockIdx.x * 256 + threadIdx.x;
    s[threadIdx.x] = (i < n) ? cnt[i] : 0;
    __syncthreads();
    for (int off = 128; off > 0; off >>= 1) {
        if (threadIdx.x < off) s[threadIdx.x] += s[threadIdx.x + off];
        __syncthreads();
    }
    if (threadIdx.x == 0) partial[blockIdx.x] = s[0];
}

__global__ void scan2(int* __restrict__ partial, int nb) {
    __shared__ int s[512];
    int t = threadIdx.x;
    int orig = (t < nb) ? partial[t] : 0;
    s[t] = orig;
    __syncthreads();
    for (int off = 1; off < 512; off <<= 1) {
        int v = (t >= off) ? s[t - off] : 0;
        __syncthreads();
        s[t] += v;
        __syncthreads();
    }
    if (t < nb) partial[t] = s[t] - orig;  // exclusive
}

__global__ void scan3(const int* __restrict__ cnt, const int* __restrict__ partial,
                      int* __restrict__ row_start, int n) {
    __shared__ int s[256];
    int i = blockIdx.x * 256 + threadIdx.x;
    int v = (i < n) ? cnt[i] : 0;
    s[threadIdx.x] = v;
    __syncthreads();
    for (int off = 1; off < 256; off <<= 1) {
        int t = (threadIdx.x >= off) ? s[threadIdx.x - off] : 0;
        __syncthreads();
        s[threadIdx.x] += t;
        __syncthreads();
    }
    if (i < n) row_start[i] = partial[blockIdx.x] + s[threadIdx.x] - v;
}

__global__ void fill_csr(const int* __restrict__ src, const int* __restrict__ dst,
                         const int* __restrict__ row_start, int* __restrict__ cursor,
                         int* __restrict__ esrc, int E) {
    int e = blockIdx.x * blockDim.x + threadIdx.x;
    if (e < E) {
        int d = dst[e];
        int pos = row_start[d] + atomicAdd(&cursor[d], 1);
        esrc[pos] = src[e];
    }
}

// ================= split helpers =================

__device__ __forceinline__ float bfhi(unsigned u) { return __uint_as_float(u << 16); }
__device__ __forceinline__ float bflo(unsigned u) { return __uint_as_float(u & 0xFFFF0000u); }

// split 4 floats -> packed hi uint2 + lo uint2 (truncating split)
__device__ __forceinline__ void split4pack(float v0, float v1, float v2, float v3,
                                           uint2& hi, uint2& lo) {
    unsigned u0 = __float_as_uint(v0), u1 = __float_as_uint(v1);
    unsigned u2 = __float_as_uint(v2), u3 = __float_as_uint(v3);
    hi.x = (u0 >> 16) | (u1 & 0xFFFF0000u);
    hi.y = (u2 >> 16) | (u3 & 0xFFFF0000u);
    unsigned w0 = __float_as_uint(v0 - bflo(u0)), w1 = __float_as_uint(v1 - bflo(u1));
    unsigned w2 = __float_as_uint(v2 - bflo(u2)), w3 = __float_as_uint(v3 - bflo(u3));
    lo.x = (w0 >> 16) | (w1 & 0xFFFF0000u);
    lo.y = (w2 >> 16) | (w3 & 0xFFFF0000u);
}

// ================= x -> split-plane form (one-time) =================
__global__ __launch_bounds__(256) void split_x(const float* __restrict__ x,
                                               ushort_t* __restrict__ x2) {
    int idx = blockIdx.x * 256 + threadIdx.x;      // node*64 + lane
    if (idx >= NNODES * 64) return;
    int node = idx >> 6, lane = idx & 63;
    float4 v = ((const float4*)(x + (size_t)node * DIM))[lane];
    uint2 hi, lo;
    split4pack(v.x, v.y, v.z, v.w, hi, lo);
    *(uint2*)(x2 + (size_t)node * 512 + lane * 4)       = hi;
    *(uint2*)(x2 + (size_t)node * 512 + 256 + lane * 4) = lo;
}

// ================= aggregation: one wave per node, split-plane in/out =================
__global__ __launch_bounds__(256) void aggregate2(
    const int* __restrict__ esrc, const int* __restrict__ row_start,
    const int* __restrict__ cnt, const ushort_t* __restrict__ x2,
    ushort_t* __restrict__ agg2)
{
    int node = (blockIdx.x * blockDim.x + threadIdx.x) >> 6;
    int lane = threadIdx.x & 63;
    if (node >= NNODES) return;
    int start = row_start[node];
    int c = cnt[node];
    float a0 = 0.f, a1 = 0.f, a2 = 0.f, a3 = 0.f;
    for (int i = 0; i < c; i++) {
        int s = esrc[start + i];
        const uint2 h = *(const uint2*)(x2 + (size_t)s * 512 + lane * 4);
        const uint2 l = *(const uint2*)(x2 + (size_t)s * 512 + 256 + lane * 4);
        a0 += bfhi(h.x) + bfhi(l.x);
        a1 += bflo(h.x) + bflo(l.x);
        a2 += bfhi(h.y) + bfhi(l.y);
        a3 += bflo(h.y) + bflo(l.y);
    }
    float inv = (c > 0) ? 1.0f / (float)c : 0.0f;
    uint2 hi, lo;
    split4pack(a0 * inv, a1 * inv, a2 * inv, a3 * inv, hi, lo);
    *(uint2*)(agg2 + (size_t)node * 512 + lane * 4)       = hi;
    *(uint2*)(agg2 + (size_t)node * 512 + 256 + lane * 4) = lo;
}

// ========== weight split + swizzle into MFMA-fragment/LDS-linear order ==========
__global__ void conv_weights(const float* __restrict__ Wl, const float* __restrict__ Wr,
                             ushort_t* __restrict__ Bsw) {
    int idx = blockIdx.x * 256 + threadIdx.x;      // n*512 + k
    if (idx >= 256 * 512) return;
    int n = idx >> 9, k = idx & 511;
    float v = (k < DIM) ? Wl[n * DIM + k] : Wr[n * DIM + (k - DIM)];
    unsigned u = __float_as_uint(v);
    float lo = v - bflo(u);
    int ks = k >> 5, q = (k >> 3) & 3, j = k & 7;
    int ct = n >> 4, nn = n & 15;
    int base = ks * SLICE + ct * 512 + q * 128 + nn * 8 + j;
    Bsw[base]        = (ushort_t)(u >> 16);                      // hi plane
    Bsw[base + 8192] = (ushort_t)(__float_as_uint(lo) >> 16);    // lo plane
}

// ================= GEMM helpers =================

// Async direct global->LDS staging of one 32 KB B slice by a 512-thread block.
// 2048 chunks of 16 B; 4 DMA instructions per wave (uniform vmcnt contribution).
__device__ __forceinline__ void stage_b_async(const ushort_t* __restrict__ slice,
                                              ushort_t* buf, int tid) {
    const int wave = tid >> 6;
    #pragma unroll
    for (int i = 0; i < 4; i++) {
        const int c  = tid + i * 512;            // per-lane 16B chunk index
        const int cb = wave * 64 + i * 512;      // wave-uniform base chunk
        __builtin_amdgcn_global_load_lds(
            (const __attribute__((address_space(1))) u32*)(slice + (size_t)c * 8),
            (__attribute__((address_space(3))) u32*)(buf + cb * 8),
            16, 0, 0);
    }
}

// A fragments come pre-split: 4 x 16B loads (row0 hi, row0 lo, row1 hi, row1 lo).
// Rows pre-clamped -> unconditional, uniform vmcnt counts across waves.
__device__ __forceinline__ void load_afrag(const ushort_t* __restrict__ base,
                                           int r0, int r1, int kk, bf16x8* f) {
    const ushort_t* p0 = base + (size_t)r0 * 512 + kk;
    const ushort_t* p1 = base + (size_t)r1 * 512 + kk;
    f[0] = *(const bf16x8*)(p0);
    f[1] = *(const bf16x8*)(p0 + 256);
    f[2] = *(const bf16x8*)(p1);
    f[3] = *(const bf16x8*)(p1 + 256);
}

// ================= MFMA GEMM: out = [agg|xin] @ B^T + bias (split-bf16, fp32 acc) ===============
// 512 threads / 8 waves (4 row-groups x 2 col-groups); double-buffered B in LDS (64 KB)
// -> 2 independent blocks/CU.
//
// 4-PHASE K-STEP (T3 minimal port; rounds 1/2/4 were all 2-phase variants and all hit the
// known 2-phase structural ceiling ~600 TF-effective, m233):
//   k-step top:  vmcnt(0) + s_barrier  — waits only on VMEM issued 4 phases (~2K cy) earlier
//   phase p=0..3: { 4x ds_read_b128 (ct=2p,2p+1, hi/lo planes)
//                   [p==0: issue B[ks+1] staging (4 DMA) + A[ks+1] loads (4)]
//                   lgkmcnt(0); sched_barrier; setprio(1); 12 MFMA; setprio(0); s_barrier }
// The per-phase barriers create the wave role-split (some waves in MFMA while others issue
// loads) that makes counted waits + setprio effective (m218b/T5). All VMEM for step ks+1 is
// issued in phase 0, so the top-of-step drain never waits on a fresh load.
//
// Output written in-place over xin2 (block-own rows only; all A-loads landed by the last
// k-step's top vmcnt(0), and the final phase barrier precedes the epilogue).
__global__ __launch_bounds__(512, 4) void sage_gemm_mfma(
    const ushort_t* __restrict__ agg2, const ushort_t* __restrict__ xin2,
    const ushort_t* __restrict__ Bsw, const float* __restrict__ bias,
    void* __restrict__ outp, int M, int out_split)
{
    __shared__ __align__(16) ushort_t Bs[2][SLICE];

    const int tid  = threadIdx.x;
    const int lane = tid & 63;
    const int wave = tid >> 6;          // 0..7
    const int lrow = lane & 15;
    const int quad = lane >> 4;
    const int rg   = wave >> 1;         // row-group 0..3
    const int cg   = wave & 1;          // col-group 0..1

    const int rowbase = blockIdx.x * BROWS + rg * 32;
    const int r0 = min(rowbase + lrow, M - 1);        // clamped (tail stays in-block)
    const int r1 = min(rowbase + 16 + lrow, M - 1);
    const int kq = quad * 8;
    const int ctbase = cg * WCT;        // 0 or 8

    f32x4 acc[2][WCT];
    #pragma unroll
    for (int i = 0; i < 2; i++)
        #pragma unroll
        for (int j = 0; j < WCT; j++)
            acc[i][j] = (f32x4){0.f, 0.f, 0.f, 0.f};

    bf16x8 fr[2][4];                    // A frags, parity-indexed (statically unrolled)

    // prologue: B[0] staging + A[0] loads (drained at ks=0 top)
    stage_b_async(Bsw, &Bs[0][0], tid);
    load_afrag(agg2, r0, r1, kq, fr[0]);

    #pragma unroll
    for (int ks = 0; ks < KSTEPS; ks++) {
        // ---- k-step top: everything outstanding was issued at phase 0 of ks-1 ----
        __builtin_amdgcn_sched_barrier(0);
        asm volatile("s_waitcnt vmcnt(0)" ::: "memory");
        __builtin_amdgcn_s_barrier();
        __builtin_amdgcn_sched_barrier(0);

        const ushort_t* bp = &Bs[ks & 1][ctbase * 512 + lane * 8];

        #pragma unroll
        for (int p = 0; p < 4; p++) {
            const int ct0 = 2 * p, ct1 = 2 * p + 1;
            bf16x8 bh0 = *(const bf16x8*)(bp + ct0 * 512);
            bf16x8 bl0 = *(const bf16x8*)(bp + 8192 + ct0 * 512);
            bf16x8 bh1 = *(const bf16x8*)(bp + ct1 * 512);
            bf16x8 bl1 = *(const bf16x8*)(bp + 8192 + ct1 * 512);

            if (p == 0 && ks + 1 < KSTEPS) {
                const int k1 = ks + 1;
                stage_b_async(Bsw + (size_t)k1 * SLICE, &Bs[k1 & 1][0], tid);
                const ushort_t* ab = (k1 < 8) ? agg2 : xin2;
                load_afrag(ab, r0, r1, (k1 & 7) * 32 + kq, fr[k1 & 1]);
            }

            asm volatile("s_waitcnt lgkmcnt(0)" ::: "memory");
            __builtin_amdgcn_sched_barrier(0);
            __builtin_amdgcn_s_setprio(1);
            acc[0][ct0] = MFMA16(fr[ks & 1][0], bh0, acc[0][ct0], 0, 0, 0);
            acc[1][ct0] = MFMA16(fr[ks & 1][2], bh0, acc[1][ct0], 0, 0, 0);
            acc[0][ct0] = MFMA16(fr[ks & 1][1], bh0, acc[0][ct0], 0, 0, 0);
            acc[1][ct0] = MFMA16(fr[ks & 1][3], bh0, acc[1][ct0], 0, 0, 0);
            acc[0][ct0] = MFMA16(fr[ks & 1][0], bl0, acc[0][ct0], 0, 0, 0);
            acc[1][ct0] = MFMA16(fr[ks & 1][2], bl0, acc[1][ct0], 0, 0, 0);
            acc[0][ct1] = MFMA16(fr[ks & 1][0], bh1, acc[0][ct1], 0, 0, 0);
            acc[1][ct1] = MFMA16(fr[ks & 1][2], bh1, acc[1][ct1], 0, 0, 0);
            acc[0][ct1] = MFMA16(fr[ks & 1][1], bh1, acc[0][ct1], 0, 0, 0);
            acc[1][ct1] = MFMA16(fr[ks & 1][3], bh1, acc[1][ct1], 0, 0, 0);
            acc[0][ct1] = MFMA16(fr[ks & 1][0], bl1, acc[0][ct1], 0, 0, 0);
            acc[1][ct1] = MFMA16(fr[ks & 1][2], bl1, acc[1][ct1], 0, 0, 0);
            __builtin_amdgcn_s_setprio(0);
            __builtin_amdgcn_sched_barrier(0);
            __builtin_amdgcn_s_barrier();
        }
    }

    // final phase barrier already separates all A-reads from the in-place epilogue
    // ---- epilogue: bias (+relu+split for layers 1-2, f32 for layer 3) ----
    // C layout: col=lane&15, row=quad*4+reg. Row-outer / ct-inner so each row's stores
    // stream 256B-contiguous per plane (write-combine friendly; was ct-outer row-jumping).
    #pragma unroll
    for (int rt = 0; rt < 2; rt++) {
        #pragma unroll
        for (int rr = 0; rr < 4; rr++) {
            const int row = rowbase + rt * 16 + quad * 4 + rr;
            if (row < M) {
                if (out_split) {
                    ushort_t* orow = (ushort_t*)outp + (size_t)row * 512;
                    #pragma unroll
                    for (int j = 0; j < WCT; j++) {
                        const int col = (ctbase + j) * 16 + lrow;
                        float v = fmaxf(acc[rt][j][rr] + bias[col], 0.f);
                        unsigned u = __float_as_uint(v);
                        float lo = v - bflo(u);
                        orow[col]       = (ushort_t)(u >> 16);
                        orow[col + 256] = (ushort_t)(__float_as_uint(lo) >> 16);
                    }
                } else {
                    float* orow = (float*)outp + (size_t)row * DIM;
                    #pragma unroll
                    for (int j = 0; j < WCT; j++) {
                        const int col = (ctbase + j) * 16 + lrow;
                        orow[col] = acc[rt][j][rr] + bias[col];
                    }
                }
            }
        }
    }
}

extern "C" void kernel_launch(void* const* d_in, const int* in_sizes, int n_in,
                              void* d_out, int out_size, void* d_ws, size_t ws_size,
                              hipStream_t stream) {
    const int*   edge = (const int*)d_in[0];
    const int*   src  = edge;
    const int*   dst  = edge + NEDGE;
    const float* x    = (const float*)d_in[1];
    const float* Wl1  = (const float*)d_in[2];
    const float* Wr1  = (const float*)d_in[3];
    const float* b1   = (const float*)d_in[4];
    const float* Wl2  = (const float*)d_in[5];
    const float* Wr2  = (const float*)d_in[6];
    const float* b2   = (const float*)d_in[7];
    const float* Wl3  = (const float*)d_in[8];
    const float* Wr3  = (const float*)d_in[9];
    const float* b3   = (const float*)d_in[10];

    // workspace: agg2 (split-plane, N*512 ushorts = 102.4 MB) + CSR + Bsw  (~109 MB total)
    ushort_t* agg2      = (ushort_t*)d_ws;
    int*      cnt       = (int*)(agg2 + (size_t)NNODES * 512);
    int*      row_start = cnt + NNODES;
    int*      cursor    = row_start + NNODES;
    int*      partial   = cursor + NNODES;            // 512
    int*      esrc      = partial + 512;              // NEDGE
    ushort_t* Bsw       = (ushort_t*)(esrc + NEDGE);  // KSTEPS*SLICE ushorts (512 KB)

    // x2 / h1 / h2 all live in the d_out region (N*512 ushorts == N*256 f32 == out_size);
    // each GEMM rewrites it in-place (block-own rows), layer 3 leaves f32 output there.
    ushort_t* x2 = (ushort_t*)d_out;

    const int nScanBlocks = (NNODES + 255) / 256;

    // ---- CSR build (edge structure shared by all 3 layers) ----
    hipMemsetAsync(cnt, 0, NNODES * sizeof(int), stream);
    hipMemsetAsync(cursor, 0, NNODES * sizeof(int), stream);
    count_kernel<<<(NEDGE + 255) / 256, 256, 0, stream>>>(dst, cnt, NEDGE);
    scan1<<<nScanBlocks, 256, 0, stream>>>(cnt, partial, NNODES);
    scan2<<<1, 512, 0, stream>>>(partial, nScanBlocks);
    scan3<<<nScanBlocks, 256, 0, stream>>>(cnt, partial, row_start, NNODES);
    fill_csr<<<(NEDGE + 255) / 256, 256, 0, stream>>>(src, dst, row_start, cursor, esrc, NEDGE);

    split_x<<<(NNODES * 64 + 255) / 256, 256, 0, stream>>>(x, x2);

    const int aggBlocks  = (NNODES * 64 + 255) / 256;
    const int gemmBlocks = (NNODES + BROWS - 1) / BROWS;
    const int convBlocks = (256 * 512 + 255) / 256;

    // ---- layer 1 ----
    conv_weights<<<convBlocks, 256, 0, stream>>>(Wl1, Wr1, Bsw);
    aggregate2<<<aggBlocks, 256, 0, stream>>>(esrc, row_start, cnt, x2, agg2);
    sage_gemm_mfma<<<gemmBlocks, 512, 0, stream>>>(agg2, x2, Bsw, b1, (void*)x2, NNODES, 1);

    // ---- layer 2 ----
    conv_weights<<<convBlocks, 256, 0, stream>>>(Wl2, Wr2, Bsw);
    aggregate2<<<aggBlocks, 256, 0, stream>>>(esrc, row_start, cnt, x2, agg2);
    sage_gemm_mfma<<<gemmBlocks, 512, 0, stream>>>(agg2, x2, Bsw, b2, (void*)x2, NNODES, 1);

    // ---- layer 3 ----
    conv_weights<<<convBlocks, 256, 0, stream>>>(Wl3, Wr3, Bsw);
    aggregate2<<<aggBlocks, 256, 0, stream>>>(esrc, row_start, cnt, x2, agg2);
    sage_gemm_mfma<<<gemmBlocks, 512, 0, stream>>>(agg2, x2, Bsw, b3, d_out, NNODES, 0);
}